// Round 1
// baseline (632.457 us; speedup 1.0000x reference)
//
#include <hip/hip_runtime.h>
#include <stdint.h>

#define THRESH 0.5f
#define VAR0 0.1f
#define VAR1 0.2f

// ---------------------------------------------------------------------------
// Pass A: per-(b,p) best GT (argmax over N, first-wins ties) and per-(b,n)
// best prior (argmax over P, smallest-p ties) via packed u64 atomicMax.
// ---------------------------------------------------------------------------
__global__ __launch_bounds__(256) void match_kernel(
    const float* __restrict__ priors, const float* __restrict__ tboxes,
    float* __restrict__ best_ov, int* __restrict__ best_idx,
    unsigned long long* __restrict__ best_prior, int P, int NOBJ)
{
#pragma clang fp contract(off)
    __shared__ float4 tr[64];
    __shared__ unsigned long long bb[64];
    const int b = blockIdx.y;
    const int tid = threadIdx.x;
    const int p = blockIdx.x * 256 + tid;
    if (tid < NOBJ) {
        tr[tid] = ((const float4*)tboxes)[(size_t)b * NOBJ + tid];
        bb[tid] = 0ULL;
    }
    __syncthreads();

    const bool valid = (p < P);
    float ax = 0.f, ay = 0.f, bx = 0.f, by = 0.f, area_p = 0.f;
    if (valid) {
        float4 pr = ((const float4*)priors)[p];
        // point_form: p[:, :2] - p[:, 2:]/2 ; p[:, :2] + p[:, 2:]/2
        ax = pr.x - pr.z * 0.5f;
        ay = pr.y - pr.w * 0.5f;
        bx = pr.x + pr.z * 0.5f;
        by = pr.y + pr.w * 0.5f;
        area_p = (bx - ax) * (by - ay);
    }

    float bestv = -1.0f;
    int bestn = 0;
    for (int n = 0; n < NOBJ; ++n) {
        float4 t = tr[n];
        float iou = 0.0f;
        if (valid) {
            float ltx = fmaxf(t.x, ax), lty = fmaxf(t.y, ay);
            float rbx = fminf(t.z, bx), rby = fminf(t.w, by);
            float w = rbx - ltx; if (w < 0.f) w = 0.f;
            float h = rby - lty; if (h < 0.f) h = 0.f;
            float inter = w * h;
            float area_t = (t.z - t.x) * (t.w - t.y);
            iou = inter / ((area_t + area_p) - inter);
            if (iou > bestv) { bestv = iou; bestn = n; }  // first-wins ties
        }
        // pack: value bits high, (0xFFFFFFFF - p) low -> max picks smallest p on ties
        unsigned long long packed = valid
            ? ((((unsigned long long)__float_as_uint(iou)) << 32) |
               (unsigned long long)(0xFFFFFFFFu - (unsigned int)p))
            : 0ULL;
        for (int off = 32; off; off >>= 1) {
            unsigned long long o = __shfl_down(packed, off, 64);
            if (o > packed) packed = o;
        }
        if ((tid & 63) == 0) atomicMax(&bb[n], packed);
    }
    __syncthreads();
    if (tid < NOBJ) atomicMax(&best_prior[(size_t)b * NOBJ + tid], bb[tid]);
    if (valid) {
        size_t g = (size_t)b * P + p;
        best_ov[g] = bestv;
        best_idx[g] = bestn;
    }
}

// ---------------------------------------------------------------------------
// Pass B: per-batch sequential fix-up (last-wins scatter semantics).
// ---------------------------------------------------------------------------
__global__ void fixup_kernel(const unsigned long long* __restrict__ best_prior,
                             float* __restrict__ best_ov, int* __restrict__ best_idx,
                             int P, int NOBJ, int B)
{
    int b = blockIdx.x * blockDim.x + threadIdx.x;
    if (b >= B) return;
    for (int n = 0; n < NOBJ; ++n) {
        unsigned long long packed = best_prior[(size_t)b * NOBJ + n];
        unsigned int pidx = 0xFFFFFFFFu - (unsigned int)(packed & 0xFFFFFFFFu);
        best_ov[(size_t)b * P + pidx] = 2.0f;
        best_idx[(size_t)b * P + pidx] = n;
    }
}

// ---------------------------------------------------------------------------
// Pass C: per-prior conf_t, encode+smoothL1 (pos only), CE via logsumexp.
// conf_data rows staged to LDS with coalesced float4 loads (132 MB stream).
// ---------------------------------------------------------------------------
__global__ __launch_bounds__(256) void main_kernel(
    const float* __restrict__ loc_data, const float* __restrict__ conf_data,
    const float* __restrict__ priors, const float* __restrict__ tboxes,
    const int* __restrict__ labels,
    const float* __restrict__ best_ov, const int* __restrict__ best_idx,
    float* __restrict__ loss_mine,
    double* __restrict__ acc, unsigned int* __restrict__ num_pos_total,
    unsigned int* __restrict__ num_pos,
    int P, int C, int NOBJ)
{
    extern __shared__ float lds[];
    const int b = blockIdx.y;
    const int p0 = blockIdx.x * 256;
    const int tid = threadIdx.x;
    const int rows = min(256, P - p0);
    const int nflt = rows * C;
    const float* src = conf_data + ((size_t)b * P + p0) * C;

    if ((((uintptr_t)src) & 15) == 0) {
        const int n4 = nflt >> 2;
        const float4* src4 = (const float4*)src;
        for (int i = tid; i < n4; i += 256) ((float4*)lds)[i] = src4[i];
        for (int i = (n4 << 2) + tid; i < nflt; i += 256) lds[i] = src[i];
    } else {
        for (int i = tid; i < nflt; i += 256) lds[i] = src[i];
    }
    __syncthreads();

    float ll = 0.f, pc = 0.f;
    int np = 0;
    if (tid < rows) {
        const int p = p0 + tid;
        const size_t g = (size_t)b * P + p;
        float ov = best_ov[g];
        int ti = best_idx[g];
        int conf_t = 0;
        if (!(ov < THRESH)) conf_t = labels[b * NOBJ + ti] + 1;

        const float* row = lds + tid * C;   // stride 21 (odd) -> 2-way bank alias, free
        float m = row[0];
        for (int j = 1; j < C; ++j) m = fmaxf(m, row[j]);
        float s = 0.f;
        for (int j = 0; j < C; ++j) s += expf(row[j] - m);
        float ce = (logf(s) + m) - row[conf_t];

        bool pos = (conf_t > 0);
        loss_mine[g] = pos ? 0.f : ce;
        if (pos) {
            np = 1;
            pc = ce;
            float4 t = ((const float4*)tboxes)[(size_t)b * NOBJ + ti];
            float4 pr = ((const float4*)priors)[p];
            float gcx = ((t.x + t.z) * 0.5f - pr.x) / (VAR0 * pr.z);
            float gcy = ((t.y + t.w) * 0.5f - pr.y) / (VAR0 * pr.w);
            float gw  = logf((t.z - t.x) / pr.z) / VAR1;
            float gh  = logf((t.w - t.y) / pr.w) / VAR1;
            float4 ld = ((const float4*)loc_data)[g];
            float d, a;
            d = ld.x - gcx; a = fabsf(d); ll += (a < 1.f) ? 0.5f * d * d : a - 0.5f;
            d = ld.y - gcy; a = fabsf(d); ll += (a < 1.f) ? 0.5f * d * d : a - 0.5f;
            d = ld.z - gw;  a = fabsf(d); ll += (a < 1.f) ? 0.5f * d * d : a - 0.5f;
            d = ld.w - gh;  a = fabsf(d); ll += (a < 1.f) ? 0.5f * d * d : a - 0.5f;
        }
    }

    // block reduction: wave shfl then 4-wave LDS combine
    for (int off = 32; off; off >>= 1) {
        ll += __shfl_down(ll, off, 64);
        pc += __shfl_down(pc, off, 64);
        np += __shfl_down(np, off, 64);
    }
    __shared__ float sll[4], spc[4];
    __shared__ int snp[4];
    const int lane = tid & 63, wid = tid >> 6;
    if (lane == 0) { sll[wid] = ll; spc[wid] = pc; snp[wid] = np; }
    __syncthreads();
    if (tid == 0) {
        float LL = sll[0] + sll[1] + sll[2] + sll[3];
        float PC = spc[0] + spc[1] + spc[2] + spc[3];
        int NP = snp[0] + snp[1] + snp[2] + snp[3];
        if (LL != 0.f) atomicAdd(&acc[0], (double)LL);
        if (PC != 0.f) atomicAdd(&acc[1], (double)PC);
        if (NP) {
            atomicAdd(num_pos_total, (unsigned int)NP);
            atomicAdd(&num_pos[b], (unsigned int)NP);
        }
    }
}

// ---------------------------------------------------------------------------
// Pass D: per-batch radix-select of the k-th largest loss_mine value, then
// sum-over-top-k = sum{v>T} + (k - count_gt)*T  (exact, ce >= 0, pos == 0).
// ---------------------------------------------------------------------------
__global__ __launch_bounds__(1024) void select_kernel(
    const float* __restrict__ loss_mine, const unsigned int* __restrict__ num_pos,
    double* __restrict__ acc, int P, int ratio)
{
    const int b = blockIdx.x;
    const int tid = threadIdx.x;
    int np = (int)num_pos[b];
    int k = ratio * np;
    if (k > P - 1) k = P - 1;
    if (k <= 0) return;  // uniform across block

    const float* fvals = loss_mine + (size_t)b * P;
    __shared__ unsigned int hist[256];
    __shared__ unsigned int sh_sel, sh_k;

    unsigned int prefix = 0, mask = 0;
    unsigned int kk = (unsigned int)k;
    for (int shift = 24; shift >= 0; shift -= 8) {
        for (int i = tid; i < 256; i += 1024) hist[i] = 0;
        __syncthreads();
        for (int i = tid; i < P; i += 1024) {
            unsigned int v = __float_as_uint(fvals[i]);
            if ((v & mask) == prefix) atomicAdd(&hist[(v >> shift) & 255u], 1u);
        }
        __syncthreads();
        if (tid == 0) {
            unsigned int a = 0;
            int sel = 0;
            for (int bin = 255; bin >= 0; --bin) {
                unsigned int c = hist[bin];
                if (a + c >= kk) { sel = bin; sh_k = kk - a; break; }
                a += c;
            }
            sh_sel = (unsigned int)sel;
        }
        __syncthreads();
        prefix |= sh_sel << shift;
        mask |= 0xFFu << shift;
        kk = sh_k;
        __syncthreads();
    }
    const float T = __uint_as_float(prefix);

    double s = 0.0;
    unsigned int cnt = 0;
    for (int i = tid; i < P; i += 1024) {
        float v = fvals[i];
        if (v > T) { s += (double)v; cnt++; }
    }
    for (int off = 32; off; off >>= 1) {
        s += __shfl_down(s, off, 64);
        cnt += __shfl_down(cnt, off, 64);
    }
    __shared__ double sd[16];
    __shared__ unsigned int sc[16];
    const int lane = tid & 63, wid = tid >> 6;
    if (lane == 0) { sd[wid] = s; sc[wid] = cnt; }
    __syncthreads();
    if (tid == 0) {
        double S = 0.0;
        unsigned int Cn = 0;
        for (int w = 0; w < 16; ++w) { S += sd[w]; Cn += sc[w]; }
        double contrib = S + (double)((unsigned int)k - Cn) * (double)T;
        atomicAdd(&acc[1], contrib);
    }
}

// ---------------------------------------------------------------------------
// Pass E: finalize.
// ---------------------------------------------------------------------------
__global__ void finalize_kernel(const double* __restrict__ acc,
                                const unsigned int* __restrict__ npt,
                                float* __restrict__ out)
{
    unsigned int n = *npt;
    if (n < 1u) n = 1u;
    double N = (double)n;
    out[0] = (float)(acc[0] / N);
    out[1] = (float)(acc[1] / N);
}

extern "C" void kernel_launch(void* const* d_in, const int* in_sizes, int n_in,
                              void* d_out, int out_size, void* d_ws, size_t ws_size,
                              hipStream_t stream)
{
    const float* loc_data  = (const float*)d_in[0];
    const float* conf_data = (const float*)d_in[1];
    const float* priors    = (const float*)d_in[2];
    const float* tboxes    = (const float*)d_in[3];
    const int*   tlabels   = (const int*)d_in[4];

    const int P = in_sizes[2] / 4;
    const int B = (int)((long long)in_sizes[0] / ((long long)P * 4));
    const int C = (int)((long long)in_sizes[1] / ((long long)B * P));
    const int NOBJ = in_sizes[4] / B;

    char* ws = (char*)d_ws;
    double* acc = (double*)ws;                                   // [0]=loss_l [1]=loss_c
    unsigned int* npt = (unsigned int*)(ws + 16);
    unsigned int* npos = (unsigned int*)(ws + 64);               // B uints
    unsigned long long* best_prior = (unsigned long long*)(ws + 4096);
    size_t off = 4096 + (size_t)B * NOBJ * 8;
    off = (off + 255) & ~(size_t)255;
    float* best_ov = (float*)(ws + off);
    off += (size_t)B * P * 4; off = (off + 255) & ~(size_t)255;
    int* best_idx = (int*)(ws + off);
    off += (size_t)B * P * 4; off = (off + 255) & ~(size_t)255;
    float* loss_mine = (float*)(ws + off);

    // zero accumulators + best_prior packed array
    hipMemsetAsync(ws, 0, 4096 + (size_t)B * NOBJ * 8, stream);

    dim3 grid((P + 255) / 256, B);
    match_kernel<<<grid, 256, 0, stream>>>(priors, tboxes, best_ov, best_idx,
                                           best_prior, P, NOBJ);
    fixup_kernel<<<(B + 63) / 64, 64, 0, stream>>>(best_prior, best_ov, best_idx,
                                                   P, NOBJ, B);
    size_t smem = (size_t)256 * C * sizeof(float);
    main_kernel<<<grid, 256, smem, stream>>>(loc_data, conf_data, priors, tboxes,
                                             tlabels, best_ov, best_idx, loss_mine,
                                             acc, npt, npos, P, C, NOBJ);
    select_kernel<<<B, 1024, 0, stream>>>(loss_mine, npos, acc, P, 3);
    finalize_kernel<<<1, 1, 0, stream>>>(acc, npt, (float*)d_out);
}

// Round 2
// 365.298 us; speedup vs baseline: 1.7313x; 1.7313x over previous
//
#include <hip/hip_runtime.h>
#include <stdint.h>

#define THRESH 0.5f
#define VAR0 0.1f
#define VAR1 0.2f

// ---------------------------------------------------------------------------
// Pass A: per-(b,p) best GT (argmax over N, first-wins) written to
// best_ov/best_idx, plus per-(b,block,n) best-prior candidates written to
// part_best (plain stores, no atomics). In-block per-n reduce via LDS
// transpose instead of u64 shuffles.
// ---------------------------------------------------------------------------
__global__ __launch_bounds__(256) void match_a_kernel(
    const float* __restrict__ priors, const float* __restrict__ tboxes,
    float* __restrict__ best_ov, int* __restrict__ best_idx,
    unsigned long long* __restrict__ part_best,  // [B][NBLK][NOBJ]
    int P, int NOBJ, int NBLK)
{
#pragma clang fp contract(off)
    __shared__ float4 tr[64];
    __shared__ float siou[32 * 257];            // [n][slot], pad 257
    __shared__ unsigned long long sp[32][9];    // [n][chunk], pad 9
    const int b = blockIdx.y;
    const int bx = blockIdx.x;
    const int tid = threadIdx.x;
    const int p = bx * 256 + tid;
    if (tid < NOBJ) tr[tid] = ((const float4*)tboxes)[(size_t)b * NOBJ + tid];
    __syncthreads();

    const bool valid = (p < P);
    float ax = 0.f, ay = 0.f, bxx = 0.f, byy = 0.f, area_p = 0.f;
    if (valid) {
        float4 pr = ((const float4*)priors)[p];
        ax = pr.x - pr.z * 0.5f;
        ay = pr.y - pr.w * 0.5f;
        bxx = pr.x + pr.z * 0.5f;
        byy = pr.y + pr.w * 0.5f;
        area_p = (bxx - ax) * (byy - ay);
    }

    float bestv = -1.0f;
    int bestn = 0;
    for (int n = 0; n < NOBJ; ++n) {
        float4 t = tr[n];
        float iou = -1.0f;
        if (valid) {
            float ltx = fmaxf(t.x, ax), lty = fmaxf(t.y, ay);
            float rbx = fminf(t.z, bxx), rby = fminf(t.w, byy);
            float w = rbx - ltx; if (w < 0.f) w = 0.f;
            float h = rby - lty; if (h < 0.f) h = 0.f;
            float inter = w * h;
            float area_t = (t.z - t.x) * (t.w - t.y);
            iou = inter / ((area_t + area_p) - inter);
            if (iou > bestv) { bestv = iou; bestn = n; }   // first-wins ties
        }
        siou[n * 257 + tid] = iou;
    }
    __syncthreads();

    // stage 1: thread (n = tid&31, c = tid>>5) reduces slots [c*32, c*32+32)
    {
        const int n = tid & 31, c = tid >> 5;
        if (n < NOBJ) {
            float bv = -1.0f;
            int bs = 0;
            const int base = n * 257 + c * 32;
            for (int j = 0; j < 32; ++j) {
                float v = siou[base + j];
                if (v > bv) { bv = v; bs = c * 32 + j; }   // smallest slot on ties
            }
            unsigned long long pk = 0ULL;
            if (bv >= 0.f) {
                unsigned int pp = (unsigned int)(bx * 256 + bs);
                pk = (((unsigned long long)__float_as_uint(bv)) << 32) |
                     (unsigned long long)(0xFFFFFFFFu - pp);
            }
            sp[n][c] = pk;
        }
    }
    __syncthreads();
    if (tid < NOBJ) {
        unsigned long long best = 0ULL;
        for (int j = 0; j < 8; ++j) {
            unsigned long long v = sp[tid][j];
            if (v > best) best = v;
        }
        part_best[((size_t)b * NBLK + bx) * NOBJ + tid] = best;
    }
    if (valid) {
        size_t g = (size_t)b * P + p;
        best_ov[g] = bestv;
        best_idx[g] = bestn;
    }
}

// ---------------------------------------------------------------------------
// Pass B: reduce part_best over blocks -> best_prior[b][n]. Plain stores.
// ---------------------------------------------------------------------------
__global__ __launch_bounds__(256) void match_b_kernel(
    const unsigned long long* __restrict__ part_best,
    unsigned long long* __restrict__ best_prior,
    int NOBJ, int NBLK, int total)
{
    int idx = blockIdx.x * 256 + threadIdx.x;
    if (idx >= total) return;
    int b = idx / NOBJ;
    int n = idx - b * NOBJ;
    unsigned long long best = 0ULL;
    const unsigned long long* src = part_best + (size_t)b * NBLK * NOBJ + n;
    for (int j = 0; j < NBLK; ++j) {
        unsigned long long v = src[(size_t)j * NOBJ];
        if (v > best) best = v;
    }
    best_prior[idx] = best;
}

// ---------------------------------------------------------------------------
// Pass C: per-batch sequential fix-up (last-wins scatter semantics).
// ---------------------------------------------------------------------------
__global__ void fixup_kernel(const unsigned long long* __restrict__ best_prior,
                             float* __restrict__ best_ov, int* __restrict__ best_idx,
                             int P, int NOBJ, int B)
{
    int b = blockIdx.x * blockDim.x + threadIdx.x;
    if (b >= B) return;
    for (int n = 0; n < NOBJ; ++n) {
        unsigned long long packed = best_prior[(size_t)b * NOBJ + n];
        unsigned int pidx = 0xFFFFFFFFu - (unsigned int)(packed & 0xFFFFFFFFu);
        best_ov[(size_t)b * P + pidx] = 2.0f;
        best_idx[(size_t)b * P + pidx] = n;
    }
}

// ---------------------------------------------------------------------------
// Pass D: conf_t, encode+smoothL1 (pos only), CE via logsumexp. Per-block
// partials stored to private slots — NO global atomics.
// ---------------------------------------------------------------------------
__global__ __launch_bounds__(256) void main_kernel(
    const float* __restrict__ loc_data, const float* __restrict__ conf_data,
    const float* __restrict__ priors, const float* __restrict__ tboxes,
    const int* __restrict__ labels,
    const float* __restrict__ best_ov, const int* __restrict__ best_idx,
    float* __restrict__ loss_mine,
    float* __restrict__ ll_part, float* __restrict__ pc_part,
    int* __restrict__ np_part,
    int P, int C, int NOBJ, int NBLK)
{
    extern __shared__ float lds[];
    const int b = blockIdx.y;
    const int bx = blockIdx.x;
    const int p0 = bx * 256;
    const int tid = threadIdx.x;
    const int rows = min(256, P - p0);
    const int nflt = rows * C;
    const float* src = conf_data + ((size_t)b * P + p0) * C;

    if ((((uintptr_t)src) & 15) == 0) {
        const int n4 = nflt >> 2;
        const float4* src4 = (const float4*)src;
        for (int i = tid; i < n4; i += 256) ((float4*)lds)[i] = src4[i];
        for (int i = (n4 << 2) + tid; i < nflt; i += 256) lds[i] = src[i];
    } else {
        for (int i = tid; i < nflt; i += 256) lds[i] = src[i];
    }
    __syncthreads();

    float ll = 0.f, pc = 0.f;
    int np = 0;
    if (tid < rows) {
        const int p = p0 + tid;
        const size_t g = (size_t)b * P + p;
        float ov = best_ov[g];
        int ti = best_idx[g];
        int conf_t = 0;
        if (!(ov < THRESH)) conf_t = labels[b * NOBJ + ti] + 1;

        const float* row = lds + tid * C;   // stride 21 (odd): 2-way alias, free
        float m = row[0];
        for (int j = 1; j < C; ++j) m = fmaxf(m, row[j]);
        float s = 0.f;
        for (int j = 0; j < C; ++j) s += expf(row[j] - m);
        float ce = (logf(s) + m) - row[conf_t];

        bool pos = (conf_t > 0);
        loss_mine[g] = pos ? 0.f : ce;
        if (pos) {
            np = 1;
            pc = ce;
            float4 t = ((const float4*)tboxes)[(size_t)b * NOBJ + ti];
            float4 pr = ((const float4*)priors)[p];
            float gcx = ((t.x + t.z) * 0.5f - pr.x) / (VAR0 * pr.z);
            float gcy = ((t.y + t.w) * 0.5f - pr.y) / (VAR0 * pr.w);
            float gw  = logf((t.z - t.x) / pr.z) / VAR1;
            float gh  = logf((t.w - t.y) / pr.w) / VAR1;
            float4 ld = ((const float4*)loc_data)[g];
            float d, a;
            d = ld.x - gcx; a = fabsf(d); ll += (a < 1.f) ? 0.5f * d * d : a - 0.5f;
            d = ld.y - gcy; a = fabsf(d); ll += (a < 1.f) ? 0.5f * d * d : a - 0.5f;
            d = ld.z - gw;  a = fabsf(d); ll += (a < 1.f) ? 0.5f * d * d : a - 0.5f;
            d = ld.w - gh;  a = fabsf(d); ll += (a < 1.f) ? 0.5f * d * d : a - 0.5f;
        }
    }

    for (int off = 32; off; off >>= 1) {
        ll += __shfl_down(ll, off, 64);
        pc += __shfl_down(pc, off, 64);
        np += __shfl_down(np, off, 64);
    }
    __shared__ float sll[4], spc[4];
    __shared__ int snp[4];
    const int lane = tid & 63, wid = tid >> 6;
    if (lane == 0) { sll[wid] = ll; spc[wid] = pc; snp[wid] = np; }
    __syncthreads();
    if (tid == 0) {
        size_t slot = (size_t)b * NBLK + bx;
        ll_part[slot] = sll[0] + sll[1] + sll[2] + sll[3];
        pc_part[slot] = spc[0] + spc[1] + spc[2] + spc[3];
        np_part[slot] = snp[0] + snp[1] + snp[2] + snp[3];
    }
}

// ---------------------------------------------------------------------------
// Pass E: per-batch radix-select of k-th largest loss_mine; neg-loss sum =
// sum{v>T} + (k-count)*T (exact: ce>=0, positives are exactly 0).
// Parallel suffix-scan replaces the serial bin walk.
// ---------------------------------------------------------------------------
__global__ __launch_bounds__(1024) void select_kernel(
    const float* __restrict__ loss_mine, const int* __restrict__ np_part,
    double* __restrict__ neg, int P, int ratio, int NBLK)
{
    const int b = blockIdx.x;
    const int tid = threadIdx.x;

    __shared__ int snp;
    __shared__ unsigned int histA[256], histB[256];
    __shared__ unsigned int sh_sel, sh_k;

    if (tid == 0) snp = 0;
    __syncthreads();
    if (tid < NBLK) atomicAdd(&snp, np_part[b * NBLK + tid]);
    __syncthreads();
    int k = ratio * snp;
    if (k > P - 1) k = P - 1;
    if (k <= 0) {
        if (tid == 0) neg[b] = 0.0;
        return;  // uniform across block
    }

    const float* fvals = loss_mine + (size_t)b * P;
    unsigned int prefix = 0, mask = 0;
    unsigned int kk = (unsigned int)k;
    for (int shift = 24; shift >= 0; shift -= 8) {
        if (tid < 256) histA[tid] = 0;
        __syncthreads();
        for (int i = tid; i < P; i += 1024) {
            unsigned int v = __float_as_uint(fvals[i]);
            if ((v & mask) == prefix) atomicAdd(&histA[(v >> shift) & 255u], 1u);
        }
        __syncthreads();
        // inclusive suffix sum over 256 bins (Hillis-Steele, ping-pong)
        unsigned int* s = histA;
        unsigned int* d = histB;
        for (int step = 1; step < 256; step <<= 1) {
            if (tid < 256)
                d[tid] = s[tid] + ((tid + step < 256) ? s[tid + step] : 0u);
            __syncthreads();
            unsigned int* t = s; s = d; d = t;
        }
        if (tid < 256) {
            unsigned int S = s[tid];
            unsigned int Sn = (tid < 255) ? s[tid + 1] : 0u;
            if (S >= kk && Sn < kk) { sh_sel = (unsigned int)tid; sh_k = kk - Sn; }
        }
        __syncthreads();
        prefix |= sh_sel << shift;
        mask |= 0xFFu << shift;
        kk = sh_k;
        __syncthreads();
    }
    const float T = __uint_as_float(prefix);

    double sum = 0.0;
    unsigned int cnt = 0;
    for (int i = tid; i < P; i += 1024) {
        float v = fvals[i];
        if (v > T) { sum += (double)v; cnt++; }
    }
    for (int off = 32; off; off >>= 1) {
        sum += __shfl_down(sum, off, 64);
        cnt += __shfl_down(cnt, off, 64);
    }
    __shared__ double sd[16];
    __shared__ unsigned int sc[16];
    const int lane = tid & 63, wid = tid >> 6;
    if (lane == 0) { sd[wid] = sum; sc[wid] = cnt; }
    __syncthreads();
    if (tid == 0) {
        double S = 0.0;
        unsigned int Cn = 0;
        for (int w = 0; w < 16; ++w) { S += sd[w]; Cn += sc[w]; }
        neg[b] = S + (double)((unsigned int)k - Cn) * (double)T;
    }
}

// ---------------------------------------------------------------------------
// Pass F: finalize — sum all partials, divide by N.
// ---------------------------------------------------------------------------
__global__ __launch_bounds__(256) void finalize_kernel(
    const float* __restrict__ ll_part, const float* __restrict__ pc_part,
    const int* __restrict__ np_part, const double* __restrict__ neg,
    float* __restrict__ out, int NPART, int B)
{
    const int tid = threadIdx.x;
    double ll = 0.0, pc = 0.0, ng = 0.0;
    long long np = 0;
    for (int i = tid; i < NPART; i += 256) {
        ll += (double)ll_part[i];
        pc += (double)pc_part[i];
        np += (long long)np_part[i];
    }
    for (int i = tid; i < B; i += 256) ng += neg[i];

    for (int off = 32; off; off >>= 1) {
        ll += __shfl_down(ll, off, 64);
        pc += __shfl_down(pc, off, 64);
        ng += __shfl_down(ng, off, 64);
        np += __shfl_down(np, off, 64);
    }
    __shared__ double sll[4], spc[4], sng[4];
    __shared__ long long snp[4];
    const int lane = tid & 63, wid = tid >> 6;
    if (lane == 0) { sll[wid] = ll; spc[wid] = pc; sng[wid] = ng; snp[wid] = np; }
    __syncthreads();
    if (tid == 0) {
        double LL = sll[0] + sll[1] + sll[2] + sll[3];
        double PC = spc[0] + spc[1] + spc[2] + spc[3];
        double NG = sng[0] + sng[1] + sng[2] + sng[3];
        long long NP = snp[0] + snp[1] + snp[2] + snp[3];
        if (NP < 1) NP = 1;
        double N = (double)NP;
        out[0] = (float)(LL / N);
        out[1] = (float)((PC + NG) / N);
    }
}

extern "C" void kernel_launch(void* const* d_in, const int* in_sizes, int n_in,
                              void* d_out, int out_size, void* d_ws, size_t ws_size,
                              hipStream_t stream)
{
    const float* loc_data  = (const float*)d_in[0];
    const float* conf_data = (const float*)d_in[1];
    const float* priors    = (const float*)d_in[2];
    const float* tboxes    = (const float*)d_in[3];
    const int*   tlabels   = (const int*)d_in[4];

    const int P = in_sizes[2] / 4;
    const int B = (int)((long long)in_sizes[0] / ((long long)P * 4));
    const int C = (int)((long long)in_sizes[1] / ((long long)B * P));
    const int NOBJ = in_sizes[4] / B;
    const int NBLK = (P + 255) / 256;

    char* ws = (char*)d_ws;
    size_t off = 0;
    double* neg = (double*)(ws + off);            off += (size_t)B * 8;
    off = (off + 255) & ~(size_t)255;
    float* ll_part = (float*)(ws + off);          off += (size_t)B * NBLK * 4;
    off = (off + 255) & ~(size_t)255;
    float* pc_part = (float*)(ws + off);          off += (size_t)B * NBLK * 4;
    off = (off + 255) & ~(size_t)255;
    int* np_part = (int*)(ws + off);              off += (size_t)B * NBLK * 4;
    off = (off + 255) & ~(size_t)255;
    unsigned long long* best_prior = (unsigned long long*)(ws + off);
    off += (size_t)B * NOBJ * 8;
    off = (off + 255) & ~(size_t)255;
    unsigned long long* part_best = (unsigned long long*)(ws + off);
    off += (size_t)B * NBLK * NOBJ * 8;
    off = (off + 255) & ~(size_t)255;
    float* best_ov = (float*)(ws + off);          off += (size_t)B * P * 4;
    off = (off + 255) & ~(size_t)255;
    int* best_idx = (int*)(ws + off);             off += (size_t)B * P * 4;
    off = (off + 255) & ~(size_t)255;
    float* loss_mine = (float*)(ws + off);

    dim3 grid(NBLK, B);
    match_a_kernel<<<grid, 256, 0, stream>>>(priors, tboxes, best_ov, best_idx,
                                             part_best, P, NOBJ, NBLK);
    int total = B * NOBJ;
    match_b_kernel<<<(total + 255) / 256, 256, 0, stream>>>(part_best, best_prior,
                                                            NOBJ, NBLK, total);
    fixup_kernel<<<(B + 63) / 64, 64, 0, stream>>>(best_prior, best_ov, best_idx,
                                                   P, NOBJ, B);
    size_t smem = (size_t)256 * C * sizeof(float);
    main_kernel<<<grid, 256, smem, stream>>>(loc_data, conf_data, priors, tboxes,
                                             tlabels, best_ov, best_idx, loss_mine,
                                             ll_part, pc_part, np_part,
                                             P, C, NOBJ, NBLK);
    select_kernel<<<B, 1024, 0, stream>>>(loss_mine, np_part, neg, P, 3, NBLK);
    finalize_kernel<<<1, 256, 0, stream>>>(ll_part, pc_part, np_part, neg,
                                           (float*)d_out, B * NBLK, B);
}